// Round 8
// baseline (70.917 us; speedup 1.0000x reference)
//
#include <hip/hip_runtime.h>

#define L_TOTAL 32768
#define D_MODEL 1024
#define NCH     128                      // signal chunks
#define LCH     (L_TOTAL / NCH)          // 256 l's per chunk
#define NBLK_S  (NCH * 8)                // 1024 blocks: (chunk c, d-octant q)
                                         // 4 blocks/CU -> 16 waves/CU

// K1: part[c][d] = sum_{l in chunk c} sin(2*pi*x[l]*(t[d]+log1p(l)))
// Block (c,q): 256 thr = 128 d's x 2 l-halves; 128 iters/thread, 16 waves/CU
// (R7 had only 8 waves/CU -- occupancy was the K1 limiter).
// Wave-uniform LDS broadcast loop, 4 accumulators, non-atomic coalesced store.
__global__ __launch_bounds__(256) void signal_kernel(const float* __restrict__ x,
                                                     float* __restrict__ part) {
    __shared__ float2 sxp[LCH];            // {x[l], x[l]*log1p(l)}  2 KB
    __shared__ float  hred[256];           // l-half combine         1 KB
    const int tid = threadIdx.x;
    const int c   = blockIdx.x >> 3;       // chunk 0..127
    const int q   = blockIdx.x & 7;        // d-octant 0..7

    {   // stage 256 {x, x*log1p} pairs (1 per thread)
        const int l = c * LCH + tid;
        const float xv = x[l];
        sxp[tid] = make_float2(xv, xv * __logf(1.0f + (float)l));
    }
    __syncthreads();

    const int   dl = tid & 127;            // d-local
    const int   h  = tid >> 7;             // l-half 0/1 (wave-uniform)
    const float t  = (float)(q * 128 + dl) * (1.0f / 1023.0f);  // linspace(0,1,1024)

    float a0 = 0.f, a1 = 0.f, a2 = 0.f, a3 = 0.f;
    #pragma unroll 4
    for (int j = 0; j < 128; j += 4) {     // wave-uniform broadcast reads
        const float2 v0 = sxp[h * 128 + j + 0];
        const float2 v1 = sxp[h * 128 + j + 1];
        const float2 v2 = sxp[h * 128 + j + 2];
        const float2 v3 = sxp[h * 128 + j + 3];
        a0 += __builtin_amdgcn_sinf(__builtin_amdgcn_fractf(fmaf(v0.x, t, v0.y)));
        a1 += __builtin_amdgcn_sinf(__builtin_amdgcn_fractf(fmaf(v1.x, t, v1.y)));
        a2 += __builtin_amdgcn_sinf(__builtin_amdgcn_fractf(fmaf(v2.x, t, v2.y)));
        a3 += __builtin_amdgcn_sinf(__builtin_amdgcn_fractf(fmaf(v3.x, t, v3.y)));
    }
    hred[tid] = (a0 + a1) + (a2 + a3);
    __syncthreads();
    if (tid < 128)                         // combine l-halves; coalesced 512 B store
        part[c * D_MODEL + q * 128 + tid] = hred[tid] + hred[128 + tid];
}

// K2: 128 blocks x 1024 thr. Each block redundantly reduces part (512 KB, L2-hot;
// 64 MB aggregate ~2 us) -> signal in LDS, then matvec rows 8b..8b+7.
__global__ __launch_bounds__(1024) void finish_kernel(const float* __restrict__ W,
                                                      const float* __restrict__ b,
                                                      const float* __restrict__ part,
                                                      float* __restrict__ out) {
    __shared__ float4 red[4][256];         // 16 KB: [c-slice][d-quad]
    __shared__ float4 ssig[256];           // signal as float4       4 KB
    __shared__ float  rsum[16];

    const int tid = threadIdx.x;
    const int blk = blockIdx.x;

    // phase A: signal[d] = sum_{c=0..127} part[c][d]; thread = (c-slice, d-quad)
    {
        const int dq = tid & 255;          // d-quad 0..255
        const int cs = tid >> 8;           // c-slice 0..3 (32 chunks each)
        const float4* p4 = (const float4*)part;   // [128][256]
        float4 A = make_float4(0.f, 0.f, 0.f, 0.f);
        float4 B = make_float4(0.f, 0.f, 0.f, 0.f);
        #pragma unroll
        for (int j = 0; j < 32; j += 2) {  // coalesced: consecutive tid -> consec 16B
            const float4 u = p4[(cs * 32 + j) * 256 + dq];
            const float4 v = p4[(cs * 32 + j + 1) * 256 + dq];
            A.x += u.x; A.y += u.y; A.z += u.z; A.w += u.w;
            B.x += v.x; B.y += v.y; B.z += v.z; B.w += v.w;
        }
        A.x += B.x; A.y += B.y; A.z += B.z; A.w += B.w;
        red[cs][dq] = A;
    }
    __syncthreads();
    if (tid < 256) {
        const float4 r0 = red[0][tid], r1 = red[1][tid];
        const float4 r2 = red[2][tid], r3 = red[3][tid];
        ssig[tid] = make_float4((r0.x + r1.x) + (r2.x + r3.x),
                                (r0.y + r1.y) + (r2.y + r3.y),
                                (r0.z + r1.z) + (r2.z + r3.z),
                                (r0.w + r1.w) + (r2.w + r3.w));
    }
    __syncthreads();

    // phase B: out[r] = b[r] + dot(signal, W[r,:]), r = 8*blk + (wv>>1)
    const int  wv   = tid >> 6;            // 0..15
    const int  lane = tid & 63;
    const int  h    = wv & 1;              // row half (512 floats = 128 float4)
    const int  row  = blk * 8 + (wv >> 1);
    const float4* Wr = (const float4*)(W + (size_t)row * D_MODEL);
    float sum = 0.f;
    #pragma unroll
    for (int k = 0; k < 2; ++k) {
        const int idx = h * 128 + k * 64 + lane;
        const float4 w4 = Wr[idx];
        const float4 s4 = ssig[idx];
        sum += w4.x * s4.x + w4.y * s4.y + w4.z * s4.z + w4.w * s4.w;
    }
    #pragma unroll
    for (int off = 32; off > 0; off >>= 1)
        sum += __shfl_down(sum, off, 64);
    if (lane == 0) rsum[wv] = sum;         // rsum[row_local*2 + h]
    __syncthreads();
    if (tid < 8)
        out[blk * 8 + tid] = (rsum[tid * 2] + rsum[tid * 2 + 1]) + b[blk * 8 + tid];
}

extern "C" void kernel_launch(void* const* d_in, const int* in_sizes, int n_in,
                              void* d_out, int out_size, void* d_ws, size_t ws_size,
                              hipStream_t stream) {
    const float* x = (const float*)d_in[0];   // inputs [32768]
    const float* W = (const float*)d_in[1];   // W [1024,1024]
    const float* b = (const float*)d_in[2];   // b [1024]
    float* out    = (float*)d_out;            // [1024]
    float* part   = (float*)d_ws;             // [128][1024] partials, 512 KB

    // Two dispatches; no memset (part/out fully overwritten), no atomics, no barrier.
    signal_kernel<<<NBLK_S, 256, 0, stream>>>(x, part);
    finish_kernel<<<D_MODEL / 8, 1024, 0, stream>>>(W, b, part, out);
}

// Round 9
// 68.461 us; speedup vs baseline: 1.0359x; 1.0359x over previous
//
#include <hip/hip_runtime.h>

#define L_TOTAL 32768
#define D_MODEL 1024
#define NCH     64                       // signal chunks
#define LCH     (L_TOTAL / NCH)          // 512 l's per chunk
#define NBLK_S  (NCH * 8)                // 512 blocks: (chunk c, d-octant dq)
                                         // 2 blocks/CU -> 8 waves/CU

// K1: part[c][d] = sum_{l in chunk c} sin(2*pi*x[l]*(t[d]+log1p(l)))
// Thread owns FOUR d's (spread by 32) and 64 l's: one broadcast ds_read_b64
// feeds 4 independent fma/fract/sin/add chains -> DS ops cut 4x vs R7/R8
// (per-element ds_read was the unmodeled per-CU LDS-pipe serialization).
__global__ __launch_bounds__(256) void signal_kernel(const float* __restrict__ x,
                                                     float* __restrict__ part) {
    __shared__ float2 sxp[LCH];            // {x[l], x[l]*log1p(l)}  4 KB
    __shared__ float  hred[8][128];        // l-slice combine        4 KB
    const int tid = threadIdx.x;
    const int c   = blockIdx.x >> 3;       // chunk 0..63
    const int dq  = blockIdx.x & 7;        // d-octant 0..7 (128 d's)

    #pragma unroll
    for (int s = 0; s < 2; ++s) {          // stage 512 {x, x*log1p} pairs
        const int idx = tid + s * 256;
        const int l   = c * LCH + idx;
        const float xv = x[l];
        sxp[idx] = make_float2(xv, xv * __logf(1.0f + (float)l));
    }
    __syncthreads();

    const int dl = tid & 31;               // d-local 0..31
    const int lh = tid >> 5;               // l-slice 0..7 (64 l's each)
    const int d0 = dq * 128 + dl;
    const float t0 = (float)(d0)       * (1.0f / 1023.0f);  // linspace(0,1,1024)
    const float t1 = (float)(d0 + 32)  * (1.0f / 1023.0f);
    const float t2 = (float)(d0 + 64)  * (1.0f / 1023.0f);
    const float t3 = (float)(d0 + 96)  * (1.0f / 1023.0f);

    float a0 = 0.f, a1 = 0.f, a2 = 0.f, a3 = 0.f;
    #pragma unroll 4
    for (int j = 0; j < 64; ++j) {         // 1 ds_read -> 4 d-chains (ILP 4)
        const float2 v = sxp[lh * 64 + j]; // 2 addrs/wave: free broadcast
        a0 += __builtin_amdgcn_sinf(__builtin_amdgcn_fractf(fmaf(v.x, t0, v.y)));
        a1 += __builtin_amdgcn_sinf(__builtin_amdgcn_fractf(fmaf(v.x, t1, v.y)));
        a2 += __builtin_amdgcn_sinf(__builtin_amdgcn_fractf(fmaf(v.x, t2, v.y)));
        a3 += __builtin_amdgcn_sinf(__builtin_amdgcn_fractf(fmaf(v.x, t3, v.y)));
    }
    hred[lh][dl]      = a0;                // 2-way bank alias = free
    hred[lh][dl + 32] = a1;
    hred[lh][dl + 64] = a2;
    hred[lh][dl + 96] = a3;
    __syncthreads();
    if (tid < 128) {                       // combine 8 l-slices; conflict-free reads
        float s = 0.f;
        #pragma unroll
        for (int l2 = 0; l2 < 8; ++l2) s += hred[l2][tid];
        part[c * D_MODEL + dq * 128 + tid] = s;   // coalesced 512 B store
    }
}

// K2: 128 blocks x 1024 thr, 8 rows/block. Redundant part-reduce now 256 KB/block
// (32 MB aggregate, half of R8) -> signal in LDS, then matvec rows 8b..8b+7.
__global__ __launch_bounds__(1024) void finish_kernel(const float* __restrict__ W,
                                                      const float* __restrict__ b,
                                                      const float* __restrict__ part,
                                                      float* __restrict__ out) {
    __shared__ float4 red[4][256];         // 16 KB: [c-slice][d-quad]
    __shared__ float4 ssig[256];           // signal as float4       4 KB
    __shared__ float  rsum[16];

    const int tid = threadIdx.x;
    const int blk = blockIdx.x;

    // phase A: signal[d] = sum_{c=0..63} part[c][d]; thread = (c-slice, d-quad)
    {
        const int dq = tid & 255;          // d-quad 0..255
        const int cs = tid >> 8;           // c-slice 0..3 (16 chunks each)
        const float4* p4 = (const float4*)part;   // [64][256]
        float4 A = make_float4(0.f, 0.f, 0.f, 0.f);
        float4 B = make_float4(0.f, 0.f, 0.f, 0.f);
        #pragma unroll
        for (int j = 0; j < 16; j += 2) {  // coalesced: consec tid -> consec 16B
            const float4 u = p4[(cs * 16 + j) * 256 + dq];
            const float4 v = p4[(cs * 16 + j + 1) * 256 + dq];
            A.x += u.x; A.y += u.y; A.z += u.z; A.w += u.w;
            B.x += v.x; B.y += v.y; B.z += v.z; B.w += v.w;
        }
        A.x += B.x; A.y += B.y; A.z += B.z; A.w += B.w;
        red[cs][dq] = A;
    }
    __syncthreads();
    if (tid < 256) {
        const float4 r0 = red[0][tid], r1 = red[1][tid];
        const float4 r2 = red[2][tid], r3 = red[3][tid];
        ssig[tid] = make_float4((r0.x + r1.x) + (r2.x + r3.x),
                                (r0.y + r1.y) + (r2.y + r3.y),
                                (r0.z + r1.z) + (r2.z + r3.z),
                                (r0.w + r1.w) + (r2.w + r3.w));
    }
    __syncthreads();

    // phase B: out[r] = b[r] + dot(signal, W[r,:]), r = 8*blk + (wv>>1)
    const int  wv   = tid >> 6;            // 0..15
    const int  lane = tid & 63;
    const int  h    = wv & 1;              // row half (512 floats = 128 float4)
    const int  row  = blk * 8 + (wv >> 1);
    const float4* Wr = (const float4*)(W + (size_t)row * D_MODEL);
    float sum = 0.f;
    #pragma unroll
    for (int k = 0; k < 2; ++k) {
        const int idx = h * 128 + k * 64 + lane;
        const float4 w4 = Wr[idx];
        const float4 s4 = ssig[idx];
        sum += w4.x * s4.x + w4.y * s4.y + w4.z * s4.z + w4.w * s4.w;
    }
    #pragma unroll
    for (int off = 32; off > 0; off >>= 1)
        sum += __shfl_down(sum, off, 64);
    if (lane == 0) rsum[wv] = sum;         // rsum[row_local*2 + h]
    __syncthreads();
    if (tid < 8)
        out[blk * 8 + tid] = (rsum[tid * 2] + rsum[tid * 2 + 1]) + b[blk * 8 + tid];
}

extern "C" void kernel_launch(void* const* d_in, const int* in_sizes, int n_in,
                              void* d_out, int out_size, void* d_ws, size_t ws_size,
                              hipStream_t stream) {
    const float* x = (const float*)d_in[0];   // inputs [32768]
    const float* W = (const float*)d_in[1];   // W [1024,1024]
    const float* b = (const float*)d_in[2];   // b [1024]
    float* out    = (float*)d_out;            // [1024]
    float* part   = (float*)d_ws;             // [64][1024] partials, 256 KB

    // Two dispatches; no memset (part/out fully overwritten), no atomics, no barrier.
    signal_kernel<<<NBLK_S, 256, 0, stream>>>(x, part);
    finish_kernel<<<D_MODEL / 8, 1024, 0, stream>>>(W, b, part, out);
}